// Round 6
// baseline (158.502 us; speedup 1.0000x reference)
//
#include <hip/hip_runtime.h>

// LBP block — single fused kernel, 2 output rows per wave.
// block = 256 threads (4 waves) = (n, 8-row tile, group of 16 channels).
// Each wave owns rows hrow0, hrow0+1 and is self-sufficient: its 4 x-rows x 3
// input channels live in 12 float4 registers; the 16-channel loop is pure
// register VALU + 8 DPP halo shifts. One __syncthreads total (exp(w) table).
// og==0 blocks also emit the x-copy channels from already-loaded registers.
//
// Experiment ledger:
//  R2 FAILED  (+9us): launch_bounds cap + unroll2 + readfirstlane + nt bundle
//  R3 NEUTRAL (0):    DPP wavefront shifts replace ds_permute shuffles (kept:
//                     strictly fewer ops, bit-identical)
//  R4 FAILED  (+20us): row-streaming restructure (loads on critical path)
//  R5 NEUTRAL (+1.7): LDS x-tile + unroll1 + tree-sum (occupancy theory dead)
//  R6 (this): ISOLATED nontemporal stores on the R3 structure. The kernel's
//    effective write BW is ~2.1 TB/s while the harness's fill hits 6.5 TB/s on
//    the same buffer; theory: 140.5 MB of write-once data thrashing the 8
//    per-XCD L2s gates store retirement. nt bypasses L2 allocation.
//    Also: ews LDS reads hoisted above conv (latency hidden under conv VALU).
//
// Numerics (do not change): y = (x0*cw0 + x1*cw1) + x2*cw2 sequentially with
// FMA contraction OFF to match the numpy reference; (c - s > 0) == (c > s)
// exactly for finite floats. DPP halo (R3-verified bit-identical):
//   wave_shr:1 -> lane i gets lane i-1 (== __shfl_up 1), lane 0 gets old=0
//   wave_shl:1 -> lane i gets lane i+1 (== __shfl_down 1), lane 63 gets old=0

typedef float vfloat4 __attribute__((ext_vector_type(4)));

__device__ __forceinline__ float wave_shr1(float v) {   // lane i <- lane i-1
    return __int_as_float(
        __builtin_amdgcn_update_dpp(0, __float_as_int(v), 0x138, 0xf, 0xf, false));
}
__device__ __forceinline__ float wave_shl1(float v) {   // lane i <- lane i+1
    return __int_as_float(
        __builtin_amdgcn_update_dpp(0, __float_as_int(v), 0x130, 0xf, 0xf, false));
}

__device__ __forceinline__ void store_nt(float* p, float a, float b, float c, float d) {
    vfloat4 v; v.x = a; v.y = b; v.z = c; v.w = d;
    __builtin_nontemporal_store(v, (vfloat4*)p);
}

__global__ __launch_bounds__(256) void lbp_all(
    const float* __restrict__ x,
    const float* __restrict__ conv_w,
    const float* __restrict__ w,
    float* __restrict__ out)
{
#pragma clang fp contract(off)
    const int n     = blockIdx.z;
    const int og    = blockIdx.y;            // channels og*16 .. og*16+15
    const int tid   = threadIdx.x;
    const int lane  = tid & 63;
    const int wv    = tid >> 6;              // wave 0..3
    const int col   = lane * 4;
    const int hrow0 = blockIdx.x * 8 + wv * 2;   // wave's first output row

    __shared__ float ews[128];               // exp(w) for this block's 16 ch
    if (tid < 128) ews[tid] = expf(w[og * 128 + tid]);

    const float* xn = x + (size_t)n * 3 * 65536;

    // x rows hrow0-1 .. hrow0+2 (clamped), 3 input channels, in registers.
    float4 xr[4][3];
    #pragma unroll
    for (int r = 0; r < 4; ++r) {
        int row = hrow0 - 1 + r;
        row = row < 0 ? 0 : (row > 255 ? 255 : row);
        #pragma unroll
        for (int ch = 0; ch < 3; ++ch)
            xr[r][ch] = *(const float4*)(xn + (ch * 256 + row) * 256 + col);
    }

    if (og == 0) {  // copy channels 0..2; xr[1]=row hrow0, xr[2]=row hrow0+1
        #pragma unroll
        for (int ch = 0; ch < 3; ++ch) {
            float* cp = out + ((((size_t)n * 67 + ch) * 256 + hrow0) * 256 + col);
            store_nt(cp,       xr[1][ch].x, xr[1][ch].y, xr[1][ch].z, xr[1][ch].w);
            store_nt(cp + 256, xr[2][ch].x, xr[2][ch].y, xr[2][ch].z, xr[2][ch].w);
        }
    }

    __syncthreads();

    float* obase = out + ((((size_t)n * 67 + 3 + og * 16) * 256 + hrow0) * 256 + col);

    #pragma unroll 4
    for (int oi = 0; oi < 16; ++oi) {
        // ews reads first: ds_read latency hides under the conv VALU below.
        const float e0 = ews[oi * 8 + 0], e1 = ews[oi * 8 + 1];
        const float e2 = ews[oi * 8 + 2], e3 = ews[oi * 8 + 3];
        const float e4 = ews[oi * 8 + 4], e5 = ews[oi * 8 + 5];
        const float e6 = ews[oi * 8 + 6], e7 = ews[oi * 8 + 7];

        const int o = og * 16 + oi;
        const float cw0 = conv_w[o * 3 + 0];
        const float cw1 = conv_w[o * 3 + 1];
        const float cw2 = conv_w[o * 3 + 2];

        // Y[r][k] = y at row hrow0-1+r, col (col-1+k), k=0..5; halo via DPP.
        float Y[4][6];
        #pragma unroll
        for (int r = 0; r < 4; ++r) {
            float4 yv;
            yv.x = xr[r][0].x * cw0 + xr[r][1].x * cw1 + xr[r][2].x * cw2;
            yv.y = xr[r][0].y * cw0 + xr[r][1].y * cw1 + xr[r][2].y * cw2;
            yv.z = xr[r][0].z * cw0 + xr[r][1].z * cw1 + xr[r][2].z * cw2;
            yv.w = xr[r][0].w * cw0 + xr[r][1].w * cw1 + xr[r][2].w * cw2;
            Y[r][1] = yv.x; Y[r][2] = yv.y; Y[r][3] = yv.z; Y[r][4] = yv.w;
            Y[r][0] = wave_shr1(yv.w);   // lane 0 gets 0 -> col 0 zeroed below
            Y[r][5] = wave_shl1(yv.x);   // lane 63 gets 0 -> col 255 zeroed below
        }

        #pragma unroll
        for (int k = 0; k < 2; ++k) {        // the wave's two output rows
            const int hrow = hrow0 + k;
            float res[4];
            if (hrow == 0 || hrow == 255) {  // wave-uniform branch
                res[0] = res[1] = res[2] = res[3] = 0.f;
            } else {
                const float* up  = Y[k];
                const float* mid = Y[k + 1];
                const float* dn  = Y[k + 2];
                #pragma unroll
                for (int j = 0; j < 4; ++j) {
                    const float c = mid[j + 1];
                    float acc;
                    acc  = (c > up [j    ]) ? e0 : 0.f;   // (-1,-1)
                    acc += (c > up [j + 1]) ? e1 : 0.f;   // (-1, 0)
                    acc += (c > up [j + 2]) ? e2 : 0.f;   // (-1,+1)
                    acc += (c > mid[j    ]) ? e3 : 0.f;   // ( 0,-1)
                    acc += (c > dn [j    ]) ? e4 : 0.f;   // (+1,-1)
                    acc += (c > dn [j + 1]) ? e5 : 0.f;   // (+1, 0)
                    acc += (c > dn [j + 2]) ? e6 : 0.f;   // (+1,+1)
                    acc += (c > mid[j + 2]) ? e7 : 0.f;   // ( 0,+1)
                    res[j] = acc;
                }
                if (lane == 0)  res[0] = 0.f;   // col 0
                if (lane == 63) res[3] = 0.f;   // col 255
            }
            store_nt(obase + (size_t)oi * 65536 + (size_t)k * 256,
                     res[0], res[1], res[2], res[3]);
        }
    }
}

extern "C" void kernel_launch(void* const* d_in, const int* in_sizes, int n_in,
                              void* d_out, int out_size, void* d_ws, size_t ws_size,
                              hipStream_t stream) {
    const float* x      = (const float*)d_in[0];
    const float* conv_w = (const float*)d_in[1];
    const float* w      = (const float*)d_in[2];
    float* out          = (float*)d_out;

    dim3 grid(32, 4, 8);   // (8-row tiles, channel groups of 16, batch)
    dim3 block(256);
    hipLaunchKernelGGL(lbp_all, grid, block, 0, stream, x, conv_w, w, out);
}

// Round 7
// 156.038 us; speedup vs baseline: 1.0158x; 1.0158x over previous
//
#include <hip/hip_runtime.h>

// LBP block — R7: sequential-store restructure.
// Theory: every prior variant stored channel-major: 1KB bursts 256KB apart
// per wave (~2.2 TB/s effective write BW vs 6.4 TB/s for the harness's
// sequential fill on the SAME buffer). R6's nt-store regression shows L2 was
// merging our scattered stores (bypassing it hurt) -> the store stream is the
// suspect. R4 had sequential stores but confounded them with serialized
// global loads. R7 isolates: loads staged in LDS up-front (R5-proven), each
// wave owns ONE channel and streams 16 rows top-to-bottom -> 16KB sequential
// stores per wave.
//
// block = 1024 threads = 16 waves = 16 channels x one 16-row strip.
// grid (16 strips, 4 channel-groups, 8 batch) = 512 blocks; LDS 54KB ->
// 2 blocks/CU, est ~56 VGPR -> whole grid resident in one pass.
// og==0 waves 0..2 also copy their x channel rows (sequential, from LDS).
//
// Ledger: R2 FAILED (cap spills) | R3 NEUTRAL (DPP, kept) | R4 FAILED
// (loads on crit path) | R5 NEUTRAL (occupancy theory dead) | R6 FAILED
// (nt stores -6TB/s L2 merge) | R7: sequential stores, loads staged.
//
// Numerics (do not change): y = (x0*cw0 + x1*cw1) + x2*cw2 sequentially with
// FMA contraction OFF; (c - s > 0) == (c > s) for finite floats; sequential
// acc chain identical to baseline. DPP halo (R3-verified bit-identical):
//   wave_shr:1 -> lane i gets lane i-1, lane 0 gets old=0 (col 0 masked)
//   wave_shl:1 -> lane i gets lane i+1, lane 63 gets old=0 (col 255 masked)
// Output rows 0/255 and cols 0/255 of LBP channels are zero (reference pads).

__device__ __forceinline__ float wave_shr1(float v) {   // lane i <- lane i-1
    return __int_as_float(
        __builtin_amdgcn_update_dpp(0, __float_as_int(v), 0x138, 0xf, 0xf, false));
}
__device__ __forceinline__ float wave_shl1(float v) {   // lane i <- lane i+1
    return __int_as_float(
        __builtin_amdgcn_update_dpp(0, __float_as_int(v), 0x130, 0xf, 0xf, false));
}

__global__ __launch_bounds__(1024) void lbp_all(
    const float* __restrict__ x,
    const float* __restrict__ conv_w,
    const float* __restrict__ w,
    float* __restrict__ out)
{
#pragma clang fp contract(off)
    const int n    = blockIdx.z;
    const int og   = blockIdx.y;                 // channel group og*16..+15
    const int tid  = threadIdx.x;
    const int lane = tid & 63;
    const int wv   = tid >> 6;                   // wave 0..15
    const int col  = lane * 4;
    const int s    = blockIdx.x * 16;            // strip's first output row
    const int c    = og * 16 + wv;               // this wave's LBP channel

    __shared__ float xt[3][18][256];             // x rows s-1..s+16 (clamped), 54 KB

    const float* xn = x + (size_t)n * 3 * 65536;

    // Cooperative x-tile stage: 3456 float4s (3ch x 18 rows x 64 lane-slots).
    for (int f = tid; f < 3456; f += 1024) {
        const int ch  = f / 1152;                // 1152 float4s per channel
        const int rem = f - ch * 1152;
        const int rr  = rem >> 6;                // LDS row 0..17
        const int l4  = rem & 63;
        int gr = s - 1 + rr;
        gr = gr < 0 ? 0 : (gr > 255 ? 255 : gr);
        *(float4*)&xt[ch][rr][l4 * 4] =
            *(const float4*)(xn + (size_t)ch * 65536 + (size_t)gr * 256 + l4 * 4);
    }

    // Per-wave constants (wave-uniform) -> SGPRs.
    const float cw0 = conv_w[c * 3 + 0];
    const float cw1 = conv_w[c * 3 + 1];
    const float cw2 = conv_w[c * 3 + 2];
    float ee[8];
    #pragma unroll
    for (int i = 0; i < 8; ++i)
        ee[i] = __uint_as_float(__builtin_amdgcn_readfirstlane(
                    __float_as_uint(expf(w[c * 8 + i]))));
    const float e0 = ee[0], e1 = ee[1], e2 = ee[2], e3 = ee[3];
    const float e4 = ee[4], e5 = ee[5], e6 = ee[6], e7 = ee[7];

    __syncthreads();

    // og==0 waves 0..2: copy x channel wv, rows s..s+15 (LDS rows 1..16) —
    // also a sequential 16KB store stream.
    if (og == 0 && wv < 3) {
        float* cp = out + ((((size_t)n * 67 + wv) * 256 + s) * 256 + col);
        #pragma unroll 4
        for (int r = 0; r < 16; ++r)
            *(float4*)(cp + (size_t)r * 256) = *(const float4*)&xt[wv][r + 1][col];
    }

    float* ob = out + ((((size_t)n * 67 + 3 + c) * 256 + s) * 256 + col);

    float Y[4][6];   // rolling y-window; slot indices fold to constants

    // conv LDS row IDX (wave-uniform) into window slot SLOT.
#define CONV(SLOT, IDX) do {                                                  \
        const float4 a  = *(const float4*)&xt[0][(IDX)][col];                 \
        const float4 b  = *(const float4*)&xt[1][(IDX)][col];                 \
        const float4 cc = *(const float4*)&xt[2][(IDX)][col];                 \
        float4 yv;                                                            \
        yv.x = a.x * cw0 + b.x * cw1 + cc.x * cw2;                            \
        yv.y = a.y * cw0 + b.y * cw1 + cc.y * cw2;                            \
        yv.z = a.z * cw0 + b.z * cw1 + cc.z * cw2;                            \
        yv.w = a.w * cw0 + b.w * cw1 + cc.w * cw2;                            \
        Y[SLOT][1] = yv.x; Y[SLOT][2] = yv.y;                                 \
        Y[SLOT][3] = yv.z; Y[SLOT][4] = yv.w;                                 \
        Y[SLOT][0] = wave_shr1(yv.w);                                         \
        Y[SLOT][5] = wave_shl1(yv.x);                                         \
    } while (0)

    CONV(3, 0);    // y(s-1)
    CONV(0, 1);    // y(s)

    // 16 output rows r = s+j, j=0..15; slot rotation period 4.
#define STEP(JI) do {                                                         \
    const int j = jq + (JI);                                                  \
    const int r = s + j;                                                      \
    CONV(((JI) + 1) & 3, j + 2);                       /* y(r+1) */           \
    const float* up  = Y[((JI) + 3) & 3];              /* y(r-1) */           \
    const float* mid = Y[(JI) & 3];                    /* y(r)   */           \
    const float* dn  = Y[((JI) + 1) & 3];              /* y(r+1) */           \
    float res[4];                                                             \
    if (r == 0 || r == 255) {                          /* wave-uniform */     \
        res[0] = res[1] = res[2] = res[3] = 0.f;                              \
    } else {                                                                  \
        _Pragma("unroll")                                                     \
        for (int jj = 0; jj < 4; ++jj) {                                      \
            const float cv = mid[jj + 1];                                     \
            float acc;                                                        \
            acc  = (cv > up [jj    ]) ? e0 : 0.f;      /* (-1,-1) */          \
            acc += (cv > up [jj + 1]) ? e1 : 0.f;      /* (-1, 0) */          \
            acc += (cv > up [jj + 2]) ? e2 : 0.f;      /* (-1,+1) */          \
            acc += (cv > mid[jj    ]) ? e3 : 0.f;      /* ( 0,-1) */          \
            acc += (cv > dn [jj    ]) ? e4 : 0.f;      /* (+1,-1) */          \
            acc += (cv > dn [jj + 1]) ? e5 : 0.f;      /* (+1, 0) */          \
            acc += (cv > dn [jj + 2]) ? e6 : 0.f;      /* (+1,+1) */          \
            acc += (cv > mid[jj + 2]) ? e7 : 0.f;      /* ( 0,+1) */          \
            res[jj] = acc;                                                    \
        }                                                                     \
        if (lane == 0)  res[0] = 0.f;                  /* col 0   */          \
        if (lane == 63) res[3] = 0.f;                  /* col 255 */          \
    }                                                                         \
    *(float4*)(ob + (size_t)j * 256) =                                        \
        make_float4(res[0], res[1], res[2], res[3]);                          \
} while (0)

    #pragma unroll
    for (int jq = 0; jq < 16; jq += 4) {
        STEP(0); STEP(1); STEP(2); STEP(3);
    }
#undef STEP
#undef CONV
}

extern "C" void kernel_launch(void* const* d_in, const int* in_sizes, int n_in,
                              void* d_out, int out_size, void* d_ws, size_t ws_size,
                              hipStream_t stream) {
    const float* x      = (const float*)d_in[0];
    const float* conv_w = (const float*)d_in[1];
    const float* w      = (const float*)d_in[2];
    float* out          = (float*)d_out;

    // (16 row-strips of 16, 4 channel-groups of 16 waves, 8 batch)
    dim3 grid(16, 4, 8);
    dim3 block(1024);
    hipLaunchKernelGGL(lbp_all, grid, block, 0, stream, x, conv_w, w, out);
}